// Round 5
// baseline (739.822 us; speedup 1.0000x reference)
//
#include <hip/hip_runtime.h>
#include <math.h>

#define EPSF 1e-8f
#define Tn 512
#define Dn 64
#define NB 256
#define NT 1024

__device__ __forceinline__ float sigmoidf_(float x){ return 1.0f/(1.0f+expf(-x)); }
__device__ __forceinline__ float softplusf_(float x){ return fmaxf(x,0.0f) + log1pf(expf(-fabsf(x))); }

__device__ __forceinline__ float wrs(float v){
  #pragma unroll
  for (int off=1; off<64; off<<=1) v += __shfl_xor(v, off, 64);
  return v;
}
__device__ __forceinline__ float wrm(float v){
  #pragma unroll
  for (int off=1; off<64; off<<=1) v = fmaxf(v, __shfl_xor(v, off, 64));
  return v;
}

struct __align__(16) Smem {
  float s_i[64][4];      // [k][i] own-row sqrt(p), float4 broadcast per k
  float P[Tn*4];         // [j][i] : dot partials (half1), then exp weights
  float pv[16*4*64];     // PV partials [w][i][d]
  float redw[2][8][4];   // softmax max/sum per wave per row
  float comb[4][128];    // gate input [i][x|prev]
  float gred[64*5];      // gate dot partials, stride 5
  float tl[4];           // temperatures
  float pl[128];         // pooled local
  float h1[64];
  float hb[128];
  float combb[128];
  float cbl[64];
};

__device__ __forceinline__ void gridBarrier(unsigned* cnt, unsigned target){
  __syncthreads();
  if (threadIdx.x == 0){
    __threadfence();
    __hip_atomic_fetch_add(cnt, 1u, __ATOMIC_ACQ_REL, __HIP_MEMORY_SCOPE_AGENT);
    while (__hip_atomic_load(cnt, __ATOMIC_ACQUIRE, __HIP_MEMORY_SCOPE_AGENT) < target)
      __builtin_amdgcn_s_sleep(2);
    __threadfence();
  }
  __syncthreads();
}

// pnorm for own row; writes k-major sT, caches s into sm.s_i for next layer's dot
__device__ __forceinline__ void pnorm_w(Smem& sm, float xg, int b, int r, int i_, int d_,
                                        float* __restrict__ sTout){
  float s = softplusf_(xg);
  float sum = wrs(s);
  float p = fmaxf(s/(sum+EPSF), EPSF);
  float s2 = wrs(p);
  float sq = sqrtf(p/(s2+EPSF));
  sTout[(size_t)b*Dn*Tn + (size_t)d_*Tn + r] = sq;
  sm.s_i[d_][i_] = sq;
}

// gate dot: g_pre[d] = W[d,:] . comb[i,:] for 4 rows -> sm.gred[d*5+i]
__device__ __forceinline__ void gate_dot(Smem& sm, const float* __restrict__ Wfb, int tid, int lane){
  int dd = tid >> 4, k16 = tid & 15;
  const float4* wp = (const float4*)(Wfb + (size_t)dd*128 + k16*8);
  float4 w0 = wp[0], w1 = wp[1];
  float ga[4];
  #pragma unroll
  for (int i=0;i<4;i++){
    float4 c0 = *(const float4*)&sm.comb[i][k16*8];
    float4 c1 = *(const float4*)&sm.comb[i][k16*8+4];
    ga[i] = w0.x*c0.x + w0.y*c0.y + w0.z*c0.z + w0.w*c0.w
          + w1.x*c1.x + w1.y*c1.y + w1.z*c1.z + w1.w*c1.w;
  }
  #pragma unroll
  for (int off=1; off<16; off<<=1){
    ga[0] += __shfl_xor(ga[0],off,64); ga[1] += __shfl_xor(ga[1],off,64);
    ga[2] += __shfl_xor(ga[2],off,64); ga[3] += __shfl_xor(ga[3],off,64);
  }
  if ((lane&15)==0){
    sm.gred[dd*5+0]=ga[0]; sm.gred[dd*5+1]=ga[1];
    sm.gred[dd*5+2]=ga[2]; sm.gred[dd*5+3]=ga[3];
  }
}

// MODE 0: write x + pnorm ; 1: write x + stash o in comb (pre-basin)
// MODE 2: fbgate(next) + write x + pnorm ; 3: final residual -> out
template<int MODE>
__device__ __forceinline__ void attn_layer(Smem& sm, int tid, int wav, int lane,
    int b, int row0, int r0, int lidx,
    const float* __restrict__ xin, const float* __restrict__ sTin,
    float* __restrict__ xout, float* __restrict__ sTout,
    const float* __restrict__ res_scale,
    const float* __restrict__ Wfb, const float* __restrict__ bfb,
    const float* __restrict__ prev,
    const float* __restrict__ basin_seq, const float* __restrict__ rsg){
  int i_ = tid >> 6, d_ = lane;
  // ---- dot: thread (jj, half-k); sT reads coalesced, s_i broadcast
  {
    int jj = tid & 511, half = tid >> 9;
    const float* sp = sTin + (size_t)b*Dn*Tn + (size_t)(half*32)*Tn + jj;
    float a0=0.f,a1=0.f,a2=0.f,a3=0.f;
    #pragma unroll
    for (int kk=0; kk<32; ++kk){
      float sv = sp[(size_t)kk*Tn];
      float4 si = *(const float4*)&sm.s_i[half*32+kk][0];
      a0 = fmaf(si.x, sv, a0); a1 = fmaf(si.y, sv, a1);
      a2 = fmaf(si.z, sv, a2); a3 = fmaf(si.w, sv, a3);
    }
    if (half){
      float4 pw = {a0,a1,a2,a3};
      *(float4*)&sm.P[jj*4] = pw;
    }
    __syncthreads();
    float invT = 1.0f / fmaxf(sm.tl[lidx], 1e-6f);
    if (!half){
      float4 ph = *(const float4*)&sm.P[jj*4];
      float l0 = -2.0f*acosf(fminf(fmaxf(a0+ph.x,-1.0f+1e-6f),1.0f-1e-6f))*invT;
      float l1 = -2.0f*acosf(fminf(fmaxf(a1+ph.y,-1.0f+1e-6f),1.0f-1e-6f))*invT;
      float l2 = -2.0f*acosf(fminf(fmaxf(a2+ph.z,-1.0f+1e-6f),1.0f-1e-6f))*invT;
      float l3 = -2.0f*acosf(fminf(fmaxf(a3+ph.w,-1.0f+1e-6f),1.0f-1e-6f))*invT;
      float m0=wrm(l0), m1=wrm(l1), m2=wrm(l2), m3=wrm(l3);
      if (lane==0){ sm.redw[0][wav][0]=m0; sm.redw[0][wav][1]=m1;
                    sm.redw[0][wav][2]=m2; sm.redw[0][wav][3]=m3; }
      __syncthreads();
      float mv0=sm.redw[0][0][0], mv1=sm.redw[0][0][1], mv2=sm.redw[0][0][2], mv3=sm.redw[0][0][3];
      #pragma unroll
      for (int w=1;w<8;w++){
        mv0=fmaxf(mv0,sm.redw[0][w][0]); mv1=fmaxf(mv1,sm.redw[0][w][1]);
        mv2=fmaxf(mv2,sm.redw[0][w][2]); mv3=fmaxf(mv3,sm.redw[0][w][3]);
      }
      float e0=expf(l0-mv0), e1=expf(l1-mv1), e2=expf(l2-mv2), e3=expf(l3-mv3);
      float4 ev = {e0,e1,e2,e3};
      *(float4*)&sm.P[jj*4] = ev;
      float s0=wrs(e0), s1=wrs(e1), s2=wrs(e2), s3=wrs(e3);
      if (lane==0){ sm.redw[1][wav][0]=s0; sm.redw[1][wav][1]=s1;
                    sm.redw[1][wav][2]=s2; sm.redw[1][wav][3]=s3; }
    } else {
      __syncthreads();
    }
    __syncthreads();
  }
  // ---- PV: wave w covers 32 j's; x coalesced, P b128-broadcast per j
  {
    const float* xp = xin + (size_t)b*Tn*Dn + (size_t)(wav*32)*Dn + lane;
    float o0=0.f,o1=0.f,o2=0.f,o3=0.f;
    #pragma unroll
    for (int jj2=0; jj2<32; ++jj2){
      float xv = xp[(size_t)jj2*Dn];
      float4 pw = *(const float4*)&sm.P[(wav*32+jj2)*4];
      o0 = fmaf(pw.x, xv, o0); o1 = fmaf(pw.y, xv, o1);
      o2 = fmaf(pw.z, xv, o2); o3 = fmaf(pw.w, xv, o3);
    }
    sm.pv[(wav*4+0)*64+lane]=o0; sm.pv[(wav*4+1)*64+lane]=o1;
    sm.pv[(wav*4+2)*64+lane]=o2; sm.pv[(wav*4+3)*64+lane]=o3;
  }
  __syncthreads();
  // ---- epilogue
  float o = 0.f;
  if (tid < 256){
    float ss = 0.f;
    #pragma unroll
    for (int w=0; w<16; ++w) ss += sm.pv[(w*4+i_)*64+d_];
    float sinv = 0.f;
    #pragma unroll
    for (int w=0; w<8; ++w) sinv += sm.redw[1][w][i_];
    float attn = ss / sinv;
    float xi = xin[(size_t)(row0+i_)*Dn + d_];
    float rs = res_scale[lidx];
    o = xi + rs*(attn - xi);
  }
  if constexpr (MODE == 0){
    if (tid < 256){
      xout[(size_t)(row0+i_)*Dn + d_] = o;
      pnorm_w(sm, o, b, r0+i_, i_, d_, sTout);
    }
  } else if constexpr (MODE == 1){
    if (tid < 256){
      xout[(size_t)(row0+i_)*Dn + d_] = o;
      sm.comb[i_][d_] = o;
    }
  } else if constexpr (MODE == 2){
    if (tid < 256){
      sm.comb[i_][d_] = o;
      sm.comb[i_][64+d_] = prev[(size_t)(row0+i_)*Dn + d_];
    }
    __syncthreads();
    gate_dot(sm, Wfb, tid, lane);
    __syncthreads();
    if (tid < 256){
      float g = sigmoidf_(sm.gred[d_*5+i_] + bfb[d_]);
      float xg = o*g + sm.comb[i_][64+d_]*(1.0f-g);
      xout[(size_t)(row0+i_)*Dn + d_] = xg;
      pnorm_w(sm, xg, b, r0+i_, i_, d_, sTout);
    }
  } else {
    if (tid < 256){
      float c = 0.01f * rsg[0];
      xout[(size_t)(row0+i_)*Dn + d_] = o + c*(o - basin_seq[(size_t)(row0+i_)*Dn + d_]);
    }
  }
}

__global__ __launch_bounds__(NT) void k_persist(
    const float* __restrict__ basin_seq, const float* __restrict__ basin_coords,
    const float* __restrict__ W_temp, const float* __restrict__ b_temp,
    const float* __restrict__ res_scale, const float* __restrict__ W_fb,
    const float* __restrict__ b_fb, const float* __restrict__ Wc1,
    const float* __restrict__ bc1, const float* __restrict__ Wc2,
    const float* __restrict__ bc2, const float* __restrict__ Wu,
    const float* __restrict__ bu, const float* __restrict__ rsg,
    float* __restrict__ out, unsigned* __restrict__ cnt, float* __restrict__ pooled_g,
    float* __restrict__ sTA, float* __restrict__ sTB,
    float* __restrict__ st0, float* __restrict__ st1,
    float* __restrict__ st2, float* __restrict__ st3,
    float* __restrict__ xA, float* __restrict__ xB){
  __shared__ Smem sm;
  int tid = threadIdx.x, wav = tid>>6, lane = tid&63;
  int row0 = blockIdx.x*4;
  int b = row0 >> 9;
  int r0 = row0 & 511;
  int i_ = tid>>6, d_ = lane;
  unsigned tgt = 0;

  // ---- init: temps(pass0) + pnorm(basin_seq) for own rows
  if (tid < 256){
    float v = W_temp[wav*Dn + lane] * basin_coords[lane];
    v = wrs(v);
    if (lane==0) sm.tl[wav] = sigmoidf_(v + b_temp[wav]) + 0.5f;
  }
  if (tid < 256){
    float xv = basin_seq[(size_t)(row0+i_)*Dn + d_];
    pnorm_w(sm, xv, b, r0+i_, i_, d_, sTA);
  }
  __threadfence();
  tgt += NB; gridBarrier(cnt, tgt);

  // ---- pass 0
  attn_layer<0>(sm,tid,wav,lane,b,row0,r0, 0, basin_seq, sTA, st0, sTB,
                res_scale, nullptr,nullptr,nullptr,nullptr,nullptr);
  tgt += NB; gridBarrier(cnt, tgt);
  attn_layer<0>(sm,tid,wav,lane,b,row0,r0, 1, st0, sTB, st1, sTA,
                res_scale, nullptr,nullptr,nullptr,nullptr,nullptr);
  tgt += NB; gridBarrier(cnt, tgt);
  attn_layer<0>(sm,tid,wav,lane,b,row0,r0, 2, st1, sTA, st2, sTB,
                res_scale, nullptr,nullptr,nullptr,nullptr,nullptr);
  tgt += NB; gridBarrier(cnt, tgt);
  attn_layer<1>(sm,tid,wav,lane,b,row0,r0, 3, st2, sTB, st3, nullptr,
                res_scale, nullptr,nullptr,nullptr,nullptr,nullptr);

  // ---- pooled partial (own 4 rows) -> global atomic
  __syncthreads();
  if (tid < 64){
    float part = sm.comb[0][tid]+sm.comb[1][tid]+sm.comb[2][tid]+sm.comb[3][tid];
    atomicAdd(&pooled_g[b*64+tid], part);
  }
  __threadfence();
  tgt += NB; gridBarrier(cnt, tgt);

  // ---- basin update (redundant per block) + temps(pass1)
  if (tid < 128)
    sm.pl[tid] = __hip_atomic_load(&pooled_g[tid], __ATOMIC_RELAXED, __HIP_MEMORY_SCOPE_AGENT) * (1.0f/512.0f);
  __syncthreads();
  if (tid < 64){
    int bb=tid>>5, h=tid&31;
    float acc=0.f;
    #pragma unroll 8
    for (int d2=0; d2<64; d2++) acc += sm.pl[bb*64+d2]*Wc1[h*64+d2];
    sm.h1[tid] = tanhf(acc + bc1[h]);
  }
  __syncthreads();
  if (tid < 128){
    int bb=tid>>6, dd=tid&63;
    float acc=0.f;
    #pragma unroll 8
    for (int h2=0; h2<32; h2++) acc += sm.h1[bb*32+h2]*Wc2[dd*32+h2];
    sm.hb[tid] = tanhf(acc + bc2[dd]);
  }
  __syncthreads();
  if (tid < 64){
    float agg = 0.5f*(sm.hb[tid] + sm.hb[64+tid]);
    sm.combb[tid] = basin_coords[tid];
    sm.combb[64+tid] = agg;
  }
  __syncthreads();
  if (tid < 64){
    float acc=0.f;
    #pragma unroll 8
    for (int k=0;k<128;k++) acc += Wu[tid*128+k]*sm.combb[k];
    float g = sigmoidf_(acc + bu[tid]);
    sm.cbl[tid] = sm.combb[tid]*(1.0f-g) + sm.combb[64+tid]*g;
  }
  __syncthreads();
  if (tid < 256){
    float v = W_temp[wav*Dn + lane] * sm.cbl[lane];
    v = wrs(v);
    if (lane==0) sm.tl[wav] = sigmoidf_(v + b_temp[wav]) + 0.5f;
  }
  // ---- pass-1 layer-0 prep: fbgate(l=0) on own rows (comb[i][0:64] still holds st3)
  if (tid < 256) sm.comb[i_][64+d_] = st0[(size_t)(row0+i_)*Dn + d_];
  __syncthreads();
  gate_dot(sm, W_fb, tid, lane);
  __syncthreads();
  if (tid < 256){
    float g = sigmoidf_(sm.gred[d_*5+i_] + b_fb[d_]);
    float xg = sm.comb[i_][d_]*g + sm.comb[i_][64+d_]*(1.0f-g);
    xA[(size_t)(row0+i_)*Dn + d_] = xg;
    pnorm_w(sm, xg, b, r0+i_, i_, d_, sTA);
  }
  __threadfence();
  tgt += NB; gridBarrier(cnt, tgt);

  // ---- pass 1
  attn_layer<2>(sm,tid,wav,lane,b,row0,r0, 0, xA, sTA, xB, sTB,
                res_scale, W_fb + 1*Dn*2*Dn, b_fb + 1*Dn, st1, nullptr,nullptr);
  tgt += NB; gridBarrier(cnt, tgt);
  attn_layer<2>(sm,tid,wav,lane,b,row0,r0, 1, xB, sTB, xA, sTA,
                res_scale, W_fb + 2*Dn*2*Dn, b_fb + 2*Dn, st2, nullptr,nullptr);
  tgt += NB; gridBarrier(cnt, tgt);
  attn_layer<2>(sm,tid,wav,lane,b,row0,r0, 2, xA, sTA, xB, sTB,
                res_scale, W_fb + 3*Dn*2*Dn, b_fb + 3*Dn, st3, nullptr,nullptr);
  tgt += NB; gridBarrier(cnt, tgt);
  attn_layer<3>(sm,tid,wav,lane,b,row0,r0, 3, xB, sTB, out, nullptr,
                res_scale, nullptr,nullptr,nullptr, basin_seq, rsg);
}

extern "C" void kernel_launch(void* const* d_in, const int* in_sizes, int n_in,
                              void* d_out, int out_size, void* d_ws, size_t ws_size,
                              hipStream_t stream) {
  const float* basin_seq    = (const float*)d_in[0];
  const float* basin_coords = (const float*)d_in[1];
  const float* W_temp       = (const float*)d_in[2];
  const float* b_temp       = (const float*)d_in[3];
  const float* res_scale    = (const float*)d_in[4];
  const float* W_fb         = (const float*)d_in[5];
  const float* b_fb         = (const float*)d_in[6];
  const float* Wc1          = (const float*)d_in[7];
  const float* bc1          = (const float*)d_in[8];
  const float* Wc2          = (const float*)d_in[9];
  const float* bc2          = (const float*)d_in[10];
  const float* Wu           = (const float*)d_in[11];
  const float* bu           = (const float*)d_in[12];
  const float* rsg          = (const float*)d_in[13];
  float* out = (float*)d_out;
  float* ws  = (float*)d_ws;

  unsigned* cnt   = (unsigned*)d_ws;
  float* pooled_g = ws + 16;       // 64B in
  float* base     = ws + 256;      // 1KB in
  const size_t N  = (size_t)Tn*2*Dn; // 65536
  float* sTA = base;
  float* sTB = base + N;
  float* st0 = base + 2*N;
  float* st1 = base + 3*N;
  float* st2 = base + 4*N;
  float* st3 = base + 5*N;
  float* xA  = base + 6*N;
  float* xB  = base + 7*N;

  hipMemsetAsync(d_ws, 0, 1024, stream);   // zero barrier counter + pooled accumulator
  k_persist<<<NB, NT, 0, stream>>>(basin_seq, basin_coords, W_temp, b_temp,
                                   res_scale, W_fb, b_fb, Wc1, bc1, Wc2, bc2,
                                   Wu, bu, rsg, out, cnt, pooled_g,
                                   sTA, sTB, st0, st1, st2, st3, xA, xB);
}

// Round 6
// 184.810 us; speedup vs baseline: 4.0031x; 4.0031x over previous
//
#include <hip/hip_runtime.h>
#include <math.h>

#define EPSF 1e-8f
#define Tn 512
#define Dn 64
#define ROWS 1024
#define NELEM 65536

__device__ __forceinline__ float sigmoidf_(float x){ return 1.0f/(1.0f+expf(-x)); }
__device__ __forceinline__ float softplusf_(float x){ return fmaxf(x,0.0f) + log1pf(expf(-fabsf(x))); }

__device__ __forceinline__ float wrs(float v){
  #pragma unroll
  for (int off=1; off<64; off<<=1) v += __shfl_xor(v, off, 64);
  return v;
}
__device__ __forceinline__ float wrm(float v){
  #pragma unroll
  for (int off=1; off<64; off<<=1) v = fmaxf(v, __shfl_xor(v, off, 64));
  return v;
}

// pnorm for one row (lanes = d, one wave per row); writes row-major + k-major
__device__ __forceinline__ void pnorm_w(float xg, int b, int r, int row, int d,
                                        float* __restrict__ sbuf_out,
                                        float* __restrict__ sT_out){
  float s = softplusf_(xg);
  float sum = wrs(s);
  float p = fmaxf(s/(sum+EPSF), EPSF);
  float s2 = wrs(p);
  float sq = sqrtf(p/(s2+EPSF));
  sbuf_out[(size_t)row*Dn + d] = sq;
  sT_out[(size_t)b*Dn*Tn + (size_t)d*Tn + r] = sq;
}

// ---- prologue: pnorm(basin_seq) (blocks 0..255, 4 rows) ; temps (block 256)
__global__ __launch_bounds__(256) void k_prologue(
    const float* __restrict__ basin_seq, float* __restrict__ sA, float* __restrict__ sTA,
    const float* __restrict__ W_temp, const float* __restrict__ b_temp,
    const float* __restrict__ cb0, float* __restrict__ temps){
  int tid = threadIdx.x, wid = tid>>6, lane = tid&63;
  if (blockIdx.x < 256){
    int row = blockIdx.x*4 + wid;
    float xv = basin_seq[(size_t)row*Dn+lane];
    pnorm_w(xv, row>>9, row&511, row, lane, sA, sTA);
  } else if (tid < 64){
    float cbv = cb0[tid];
    #pragma unroll
    for (int l=0;l<4;l++){
      float v = wrs(W_temp[l*Dn + tid]*cbv);
      if (tid==0) temps[l] = sigmoidf_(v + b_temp[l]) + 0.5f;
    }
  }
}

// gate dot with 512 threads: 8 threads per output d, each dots 16 of 128
__device__ __forceinline__ void gate_dot512(float (*comb)[128], float* gred,
                                            const float* __restrict__ Wfb, int tid, int lane){
  int dd = tid >> 3, k8 = tid & 7;
  const float4* wp = (const float4*)(Wfb + (size_t)dd*128 + k8*16);
  float4 w0 = wp[0], w1 = wp[1], w2 = wp[2], w3 = wp[3];
  float ga[4];
  #pragma unroll
  for (int i=0;i<4;i++){
    float4 c0 = *(const float4*)&comb[i][k8*16];
    float4 c1 = *(const float4*)&comb[i][k8*16+4];
    float4 c2 = *(const float4*)&comb[i][k8*16+8];
    float4 c3 = *(const float4*)&comb[i][k8*16+12];
    ga[i] = w0.x*c0.x + w0.y*c0.y + w0.z*c0.z + w0.w*c0.w
          + w1.x*c1.x + w1.y*c1.y + w1.z*c1.z + w1.w*c1.w
          + w2.x*c2.x + w2.y*c2.y + w2.z*c2.z + w2.w*c2.w
          + w3.x*c3.x + w3.y*c3.y + w3.z*c3.z + w3.w*c3.w;
  }
  #pragma unroll
  for (int off=1; off<8; off<<=1){
    ga[0] += __shfl_xor(ga[0],off,64); ga[1] += __shfl_xor(ga[1],off,64);
    ga[2] += __shfl_xor(ga[2],off,64); ga[3] += __shfl_xor(ga[3],off,64);
  }
  if ((lane&7)==0){
    gred[dd*5+0]=ga[0]; gred[dd*5+1]=ga[1]; gred[dd*5+2]=ga[2]; gred[dd*5+3]=ga[3];
  }
}

// ---- QFI attention, NI=4 rows/block, 512 threads, grid 256.
// MODE 0: write x + pnorm ; 1: write x only (pre-basin)
// MODE 2: fbgate(next layer) + write x + pnorm ; 3: final residual -> out
template<int MODE>
__global__ __launch_bounds__(512) void k_attn(
    const float* __restrict__ xin, const float* __restrict__ sbuf,
    const float* __restrict__ sT, const float* __restrict__ temps,
    const float* __restrict__ res_scale, int l,
    float* __restrict__ xout, float* __restrict__ sbuf_out, float* __restrict__ sT_out,
    const float* __restrict__ Wfb, const float* __restrict__ bfb,
    const float* __restrict__ prev,
    const float* __restrict__ basin_seq, const float* __restrict__ rsg){
  __shared__ __align__(16) float s_i[64*4];   // [k][i]
  __shared__ __align__(16) float P[512*4];    // [j][i] exp weights
  __shared__ float pv[8*4*64];                // [w][i][d]
  __shared__ float redw[2][8][4];
  __shared__ __align__(16) float comb[4][128];
  __shared__ float gred[64*5];

  int tid = threadIdx.x, wav = tid>>6, lane = tid&63;
  int row0 = blockIdx.x*4, b = row0>>9, r0 = row0&511;
  int i_ = tid>>6, d_ = lane;   // epilogue mapping for tid<256

  if (tid < 256) s_i[d_*4 + i_] = sbuf[(size_t)(row0+i_)*Dn + d_];
  __syncthreads();

  float invT = 1.0f/fmaxf(temps[l], 1e-6f);
  // ---- dot: thread j = tid, full k, coalesced sT reads + s_i b128 broadcasts
  const float* sp = sT + (size_t)b*Dn*Tn + tid;
  float a0=0.f,a1=0.f,a2=0.f,a3=0.f;
  #pragma unroll 16
  for (int kk=0;kk<64;kk++){
    float sv = sp[(size_t)kk*Tn];
    float4 si = *(const float4*)&s_i[kk*4];
    a0=fmaf(si.x,sv,a0); a1=fmaf(si.y,sv,a1);
    a2=fmaf(si.z,sv,a2); a3=fmaf(si.w,sv,a3);
  }
  float l0 = -2.0f*acosf(fminf(fmaxf(a0,-1.0f+1e-6f),1.0f-1e-6f))*invT;
  float l1 = -2.0f*acosf(fminf(fmaxf(a1,-1.0f+1e-6f),1.0f-1e-6f))*invT;
  float l2 = -2.0f*acosf(fminf(fmaxf(a2,-1.0f+1e-6f),1.0f-1e-6f))*invT;
  float l3 = -2.0f*acosf(fminf(fmaxf(a3,-1.0f+1e-6f),1.0f-1e-6f))*invT;
  // ---- softmax
  float m0=wrm(l0), m1=wrm(l1), m2=wrm(l2), m3=wrm(l3);
  if (lane==0){ redw[0][wav][0]=m0; redw[0][wav][1]=m1; redw[0][wav][2]=m2; redw[0][wav][3]=m3; }
  __syncthreads();
  float mv0=redw[0][0][0], mv1=redw[0][0][1], mv2=redw[0][0][2], mv3=redw[0][0][3];
  #pragma unroll
  for (int w=1;w<8;w++){
    mv0=fmaxf(mv0,redw[0][w][0]); mv1=fmaxf(mv1,redw[0][w][1]);
    mv2=fmaxf(mv2,redw[0][w][2]); mv3=fmaxf(mv3,redw[0][w][3]);
  }
  float e0=expf(l0-mv0), e1=expf(l1-mv1), e2=expf(l2-mv2), e3=expf(l3-mv3);
  float4 ev = {e0,e1,e2,e3};
  *(float4*)&P[tid*4] = ev;
  float q0=wrs(e0), q1=wrs(e1), q2=wrs(e2), q3=wrs(e3);
  if (lane==0){ redw[1][wav][0]=q0; redw[1][wav][1]=q1; redw[1][wav][2]=q2; redw[1][wav][3]=q3; }
  __syncthreads();
  // ---- PV: wave w covers j in [w*64,(w+1)*64); x coalesced, P b128 broadcast
  {
    const float* xp = xin + (size_t)b*Tn*Dn + (size_t)(wav*64)*Dn + lane;
    float o0=0.f,o1=0.f,o2=0.f,o3=0.f;
    #pragma unroll 8
    for (int j=0;j<64;j++){
      float xv = xp[(size_t)j*Dn];
      float4 pw = *(const float4*)&P[(wav*64+j)*4];
      o0=fmaf(pw.x,xv,o0); o1=fmaf(pw.y,xv,o1);
      o2=fmaf(pw.z,xv,o2); o3=fmaf(pw.w,xv,o3);
    }
    pv[(wav*4+0)*64+lane]=o0; pv[(wav*4+1)*64+lane]=o1;
    pv[(wav*4+2)*64+lane]=o2; pv[(wav*4+3)*64+lane]=o3;
  }
  __syncthreads();
  // ---- epilogue
  float o = 0.f;
  if (tid < 256){
    float ss = 0.f;
    #pragma unroll
    for (int w=0;w<8;w++) ss += pv[(w*4+i_)*64+d_];
    float sv = 0.f;
    #pragma unroll
    for (int w=0;w<8;w++) sv += redw[1][w][i_];
    float attn = ss/sv;
    float xi = xin[(size_t)(row0+i_)*Dn + d_];
    o = xi + res_scale[l]*(attn - xi);
  }
  if constexpr (MODE == 0){
    if (tid < 256){
      xout[(size_t)(row0+i_)*Dn + d_] = o;
      pnorm_w(o, b, r0+i_, row0+i_, d_, sbuf_out, sT_out);
    }
  } else if constexpr (MODE == 1){
    if (tid < 256) xout[(size_t)(row0+i_)*Dn + d_] = o;
  } else if constexpr (MODE == 2){
    if (tid < 256){
      comb[i_][d_] = o;
      comb[i_][64+d_] = prev[(size_t)(row0+i_)*Dn + d_];
    }
    __syncthreads();
    gate_dot512(comb, gred, Wfb, tid, lane);
    __syncthreads();
    if (tid < 256){
      float g = sigmoidf_(gred[d_*5+i_] + bfb[d_]);
      float xg = o*g + comb[i_][64+d_]*(1.0f-g);
      xout[(size_t)(row0+i_)*Dn + d_] = xg;
      pnorm_w(xg, b, r0+i_, row0+i_, d_, sbuf_out, sT_out);
    }
  } else {
    if (tid < 256){
      float c = 0.01f * rsg[0];
      xout[(size_t)(row0+i_)*Dn + d_] = o + c*(o - basin_seq[(size_t)(row0+i_)*Dn + d_]);
    }
  }
}

// ---- blocks 0..255: pass-1 layer-0 fbgate + pnorm (4 rows); block 256: basin+temps
__global__ __launch_bounds__(256) void k_basinprep(
    const float* __restrict__ st3, const float* __restrict__ st0,
    const float* __restrict__ W_fb, const float* __restrict__ b_fb,
    float* __restrict__ xA, float* __restrict__ sA, float* __restrict__ sTA,
    const float* __restrict__ Wc1, const float* __restrict__ bc1,
    const float* __restrict__ Wc2, const float* __restrict__ bc2,
    const float* __restrict__ Wu,  const float* __restrict__ bu,
    const float* __restrict__ cb_in, float* __restrict__ cb_out,
    const float* __restrict__ W_temp, const float* __restrict__ b_temp,
    float* __restrict__ temps){
  int tid = threadIdx.x, wid = tid>>6, lane = tid&63;
  __shared__ __align__(16) float comb4[4][128];
  __shared__ float pooled[128];
  __shared__ float h1[64];
  __shared__ float hb[128];
  __shared__ float combb[128];
  if (blockIdx.x < 256){
    int row = blockIdx.x*4 + wid;
    float xv = st3[(size_t)row*Dn+lane];
    float pvv = st0[(size_t)row*Dn+lane];
    comb4[wid][lane] = xv; comb4[wid][64+lane] = pvv;
    __syncthreads();
    const float4* W  = (const float4*)(W_fb + (size_t)lane*128);   // l = 0
    const float4* c4 = (const float4*)comb4[wid];
    float g0=0.f,g1=0.f;
    #pragma unroll
    for (int k=0;k<32;k+=2){
      float4 w0=W[k],   c0=c4[k];
      float4 w1=W[k+1], c1=c4[k+1];
      g0 += w0.x*c0.x + w0.y*c0.y + w0.z*c0.z + w0.w*c0.w;
      g1 += w1.x*c1.x + w1.y*c1.y + w1.z*c1.z + w1.w*c1.w;
    }
    float g = sigmoidf_(g0+g1 + b_fb[lane]);
    float xg = xv*g + pvv*(1.0f-g);
    xA[(size_t)row*Dn+lane] = xg;
    pnorm_w(xg, row>>9, row&511, row, lane, sA, sTA);
  } else {
    if (tid < 128){
      int b = tid >> 6, d = tid & 63;
      float acc=0.f;
      const float* xb = st3 + (size_t)b*Tn*Dn + d;
      for (int t=0;t<Tn;t++) acc += xb[(size_t)t*Dn];
      pooled[tid] = acc * (1.0f/Tn);
    }
    __syncthreads();
    if (tid < 64){
      int b = tid >> 5, h = tid & 31;
      float acc=0.f;
      #pragma unroll 8
      for (int d2=0; d2<64; d2++) acc += pooled[b*64+d2]*Wc1[h*64+d2];
      h1[tid] = tanhf(acc + bc1[h]);
    }
    __syncthreads();
    if (tid < 128){
      int b = tid >> 6, d = tid & 63;
      float acc=0.f;
      #pragma unroll 8
      for (int h2=0; h2<32; h2++) acc += h1[b*32+h2]*Wc2[d*32+h2];
      hb[tid] = tanhf(acc + bc2[d]);
    }
    __syncthreads();
    if (tid < 64){
      float agg = 0.5f*(hb[tid] + hb[64+tid]);
      combb[tid] = cb_in[tid];
      combb[64+tid] = agg;
    }
    __syncthreads();
    if (tid < 64){
      float acc=0.f;
      #pragma unroll 8
      for (int k=0;k<128;k++) acc += Wu[tid*128+k]*combb[k];
      float g = sigmoidf_(acc + bu[tid]);
      float nb = combb[tid]*(1.0f-g) + combb[64+tid]*g;
      cb_out[tid] = nb;
      #pragma unroll
      for (int l=0;l<4;l++){
        float v = wrs(W_temp[l*Dn + tid]*nb);
        if (tid==0) temps[l] = sigmoidf_(v + b_temp[l]) + 0.5f;
      }
    }
  }
}

extern "C" void kernel_launch(void* const* d_in, const int* in_sizes, int n_in,
                              void* d_out, int out_size, void* d_ws, size_t ws_size,
                              hipStream_t stream) {
  const float* basin_seq    = (const float*)d_in[0];
  const float* basin_coords = (const float*)d_in[1];
  const float* W_temp       = (const float*)d_in[2];
  const float* b_temp       = (const float*)d_in[3];
  const float* res_scale    = (const float*)d_in[4];
  const float* W_fb         = (const float*)d_in[5];
  const float* b_fb         = (const float*)d_in[6];
  const float* Wc1          = (const float*)d_in[7];
  const float* bc1          = (const float*)d_in[8];
  const float* Wc2          = (const float*)d_in[9];
  const float* bc2          = (const float*)d_in[10];
  const float* Wu           = (const float*)d_in[11];
  const float* bu           = (const float*)d_in[12];
  const float* rsg          = (const float*)d_in[13];
  float* out = (float*)d_out;
  float* ws  = (float*)d_ws;

  const size_t N = NELEM; // 65536
  float* sA    = ws;
  float* sB    = ws + N;
  float* sTA   = ws + 2*N;
  float* sTB   = ws + 3*N;
  float* xA    = ws + 4*N;
  float* xB    = ws + 5*N;
  float* st    = ws + 6*N;
  float* temps = ws + 10*N;
  float* cb    = ws + 10*N + 64;
  float* st0 = st, *st1 = st+N, *st2 = st+2*N, *st3 = st+3*N;

  const int GA = 256;

  // ---- pass 0
  k_prologue<<<257,256,0,stream>>>(basin_seq, sA, sTA, W_temp, b_temp, basin_coords, temps);
  k_attn<0><<<GA,512,0,stream>>>(basin_seq, sA, sTA, temps, res_scale, 0, st0, sB, sTB,
                                 nullptr,nullptr,nullptr,nullptr,nullptr);
  k_attn<0><<<GA,512,0,stream>>>(st0, sB, sTB, temps, res_scale, 1, st1, sA, sTA,
                                 nullptr,nullptr,nullptr,nullptr,nullptr);
  k_attn<0><<<GA,512,0,stream>>>(st1, sA, sTA, temps, res_scale, 2, st2, sB, sTB,
                                 nullptr,nullptr,nullptr,nullptr,nullptr);
  k_attn<1><<<GA,512,0,stream>>>(st2, sB, sTB, temps, res_scale, 3, st3, nullptr, nullptr,
                                 nullptr,nullptr,nullptr,nullptr,nullptr);
  // ---- basin update + pass-1 layer-0 prep
  k_basinprep<<<257,256,0,stream>>>(st3, st0, W_fb, b_fb, xA, sA, sTA,
                                    Wc1, bc1, Wc2, bc2, Wu, bu,
                                    basin_coords, cb, W_temp, b_temp, temps);
  // ---- pass 1
  k_attn<2><<<GA,512,0,stream>>>(xA, sA, sTA, temps, res_scale, 0, xB, sB, sTB,
                                 W_fb + (size_t)1*Dn*2*Dn, b_fb + 1*Dn, st1, nullptr,nullptr);
  k_attn<2><<<GA,512,0,stream>>>(xB, sB, sTB, temps, res_scale, 1, xA, sA, sTA,
                                 W_fb + (size_t)2*Dn*2*Dn, b_fb + 2*Dn, st2, nullptr,nullptr);
  k_attn<2><<<GA,512,0,stream>>>(xA, sA, sTA, temps, res_scale, 2, xB, sB, sTB,
                                 W_fb + (size_t)3*Dn*2*Dn, b_fb + 3*Dn, st3, nullptr,nullptr);
  k_attn<3><<<GA,512,0,stream>>>(xB, sB, sTB, temps, res_scale, 3, out, nullptr, nullptr,
                                 nullptr,nullptr,nullptr, basin_seq, rsg);
}